// Round 3
// baseline (4575.469 us; speedup 1.0000x reference)
//
#include <hip/hip_runtime.h>

typedef unsigned short u16;
typedef unsigned int   u32;

// ---------- bf16 helpers (manual, RNE) ----------
__device__ __forceinline__ float bf2f(u16 u) { return __uint_as_float(((u32)u) << 16); }
__device__ __forceinline__ float bflo(u32 u) { return __uint_as_float(u << 16); }
__device__ __forceinline__ float bfhi(u32 u) { return __uint_as_float(u & 0xffff0000u); }
__device__ __forceinline__ u16 f2bf(float f) {
    u32 x = __float_as_uint(f);
    x += 0x7fffu + ((x >> 16) & 1u);   // round-to-nearest-even
    return (u16)(x >> 16);
}

#define NPOS1 400   // 20x20
#define NPOS2 36    // 6x6

// ---------- repack conv2 weights: w2t[k][co] f32, k = ci*81 + kh*9 + kw ----------
__global__ __launch_bounds__(256) void repack_w2_kernel(const float* __restrict__ w2,
                                                        float* __restrict__ w2t) {
    int idx = blockIdx.x * 256 + threadIdx.x;      // idx = k*256 + co
    int co = idx & 255;
    int k  = idx >> 8;                              // k < 20736
    w2t[idx] = w2[(size_t)co * 20736 + k];
}

// ---------- repack W: Wt[je][d][i] f32 from W[j][i][d][e] ----------
__global__ __launch_bounds__(256) void repack_W_kernel(const float* __restrict__ W,
                                                       float* __restrict__ Wt) {
    int idx = blockIdx.x * 256 + threadIdx.x;      // total 10*16*8*1152 = 1474560
    int i = idx % 1152;
    int rest = idx / 1152;
    int d = rest & 7;
    int je = rest >> 3;
    int j = je >> 4, e = je & 15;
    Wt[idx] = W[(((size_t)j * 1152 + i) * 8 + d) * 16 + e];
}

// ---------- conv1 (9x9 s1) + bias + bf16 store + BN1 stats ----------
__global__ __launch_bounds__(256) void conv1_kernel(const float* __restrict__ x,
                                                    const float* __restrict__ w1,
                                                    const float* __restrict__ b1,
                                                    u16* __restrict__ y_raw,
                                                    float* __restrict__ sum1,
                                                    float* __restrict__ sumsq1) {
    __shared__ float xs[784];
    const int b = blockIdx.x;
    const int t = threadIdx.x;          // co
    const float* xb = x + (size_t)b * 784;
    for (int idx = t; idx < 784; idx += 256) xs[idx] = xb[idx];
    float w[81];
#pragma unroll
    for (int q = 0; q < 81; ++q) w[q] = w1[(size_t)t * 81 + q];
    const float bias = b1[t];
    __syncthreads();

    float sl = 0.f, ssl = 0.f;
    u16* yb = y_raw + ((size_t)b * 256 + t) * NPOS1;
    for (int oh = 0; oh < 20; ++oh) {
        float acc[20];
#pragma unroll
        for (int ow = 0; ow < 20; ++ow) acc[ow] = bias;
#pragma unroll
        for (int kh = 0; kh < 9; ++kh) {
            const float4* rp = (const float4*)(&xs[(oh + kh) * 28]);
            float r[28];
#pragma unroll
            for (int k4 = 0; k4 < 7; ++k4) {
                float4 f = rp[k4];
                r[k4 * 4 + 0] = f.x; r[k4 * 4 + 1] = f.y;
                r[k4 * 4 + 2] = f.z; r[k4 * 4 + 3] = f.w;
            }
#pragma unroll
            for (int kw = 0; kw < 9; ++kw) {
                const float wv = w[kh * 9 + kw];
#pragma unroll
                for (int ow = 0; ow < 20; ++ow)
                    acc[ow] = fmaf(wv, r[ow + kw], acc[ow]);
            }
        }
        u16 q16[20];
#pragma unroll
        for (int ow = 0; ow < 20; ++ow) {
            u16 q = f2bf(acc[ow]);
            q16[ow] = q;
            float rv = bf2f(q);
            sl += rv; ssl += rv * rv;
        }
        u32* yo = (u32*)(yb + oh * 20);
#pragma unroll
        for (int p = 0; p < 10; ++p)
            yo[p] = (u32)q16[2 * p] | ((u32)q16[2 * p + 1] << 16);
    }
    atomicAdd(&sum1[t], sl);
    atomicAdd(&sumsq1[t], ssl);
}

// ---------- BN finalize: scale/shift from sums ----------
__global__ void finalize_bn_kernel(const float* __restrict__ sum,
                                   const float* __restrict__ sumsq,
                                   const float* __restrict__ gam,
                                   const float* __restrict__ bet,
                                   float* __restrict__ scale,
                                   float* __restrict__ shift, float inv_n) {
    int c = threadIdx.x;
    float m = sum[c] * inv_n;
    float var = sumsq[c] * inv_n - m * m;
    float sc = gam[c] * rsqrtf(var + 1e-5f);
    scale[c] = sc;
    shift[c] = bet[c] - m * sc;
}

// ---------- conv2 (9x9 s2) with BN1+ReLU folded into LDS staging; + bias + BN2 stats ----------
__global__ __launch_bounds__(256) void conv2_kernel(const u16* __restrict__ y_raw,
                                                    const float* __restrict__ w2t,
                                                    const float* __restrict__ b2,
                                                    const float* __restrict__ scale1,
                                                    const float* __restrict__ shift1,
                                                    float* __restrict__ z_raw,
                                                    float* __restrict__ sum2,
                                                    float* __restrict__ sumsq2) {
    __shared__ float ys[8 * NPOS1];       // 12.8 KB
    const int b = blockIdx.x;
    const int t = threadIdx.x;            // co
    float acc[36];
#pragma unroll
    for (int p = 0; p < 36; ++p) acc[p] = 0.f;

    for (int cc = 0; cc < 256; cc += 8) {
        __syncthreads();
        // stage 8 ci x 400, applying BN1 + ReLU
        for (int v = t; v < 800; v += 256) {
            int ci = v / 100, p4 = v - ci * 100;
            const uint2 a2 = ((const uint2*)(y_raw + ((size_t)b * 256 + cc + ci) * NPOS1))[p4];
            float sc = scale1[cc + ci], sh = shift1[cc + ci];
            float4 o;
            o.x = fmaxf(0.f, fmaf(sc, bflo(a2.x), sh));
            o.y = fmaxf(0.f, fmaf(sc, bfhi(a2.x), sh));
            o.z = fmaxf(0.f, fmaf(sc, bflo(a2.y), sh));
            o.w = fmaxf(0.f, fmaf(sc, bfhi(a2.y), sh));
            ((float4*)ys)[v] = o;
        }
        __syncthreads();

        for (int cil = 0; cil < 8; ++cil) {
            const int ci = cc + cil;
            float w[81];
#pragma unroll
            for (int q = 0; q < 81; ++q)
                w[q] = w2t[(size_t)(ci * 81 + q) * 256 + t];
            const float* yrow = &ys[cil * NPOS1];
#pragma unroll
            for (int ih = 0; ih < 19; ++ih) {
                float r[20];
                const float4* rp = (const float4*)(yrow + ih * 20);
#pragma unroll
                for (int k4 = 0; k4 < 5; ++k4) {
                    float4 f = rp[k4];
                    r[k4 * 4 + 0] = f.x; r[k4 * 4 + 1] = f.y;
                    r[k4 * 4 + 2] = f.z; r[k4 * 4 + 3] = f.w;
                }
                const int oh_lo = (ih >= 9) ? ((ih - 7) >> 1) : 0;   // ceil((ih-8)/2)
                const int oh_hi = ((ih >> 1) < 5) ? (ih >> 1) : 5;
#pragma unroll
                for (int oh = oh_lo; oh <= oh_hi; ++oh) {
                    const int kh = ih - 2 * oh;
#pragma unroll
                    for (int kw = 0; kw < 9; ++kw) {
                        const float wv = w[kh * 9 + kw];
#pragma unroll
                        for (int ow = 0; ow < 6; ++ow)
                            acc[oh * 6 + ow] = fmaf(wv, r[2 * ow + kw], acc[oh * 6 + ow]);
                    }
                }
            }
        }
    }
    const float bias = b2[t];
    float sl = 0.f, ssl = 0.f;
    float* zp = z_raw + ((size_t)b * 256 + t) * NPOS2;
#pragma unroll
    for (int p = 0; p < 36; ++p) {
        float v = acc[p] + bias;
        zp[p] = v;
        sl += v; ssl += v * v;
    }
    atomicAdd(&sum2[t], sl);
    atomicAdd(&sumsq2[t], ssl);
}

// ---------- BN2 + ReLU + capsule transpose: ut[b][d][i] f32, i = m*36+s, c = d*32+m ----------
__global__ __launch_bounds__(256) void ubuild_kernel(const float* __restrict__ z_raw,
                                                     const float* __restrict__ scale2,
                                                     const float* __restrict__ shift2,
                                                     float* __restrict__ ut) {
    const int b = blockIdx.x;
    const int t = threadIdx.x;            // c
    const int d = t >> 5, m = t & 31;
    const float sc = scale2[t], sh = shift2[t];
    const float4* zp = (const float4*)(z_raw + ((size_t)b * 256 + t) * NPOS2);
    float4* up = (float4*)(ut + ((size_t)b * 8 + d) * 1152 + m * 36);
#pragma unroll
    for (int q = 0; q < 9; ++q) {
        float4 z = zp[q];
        float4 o;
        o.x = fmaxf(0.f, fmaf(sc, z.x, sh));
        o.y = fmaxf(0.f, fmaf(sc, z.y, sh));
        o.z = fmaxf(0.f, fmaf(sc, z.z, sh));
        o.w = fmaxf(0.f, fmaf(sc, z.w, sh));
        up[q] = o;
    }
}

// ---------- u_hat[b][je][i] bf16 = sum_d ut[b][d][i] * Wt[je][d][i] ----------
__global__ __launch_bounds__(64) void uhat_kernel(const float* __restrict__ ut,
                                                  const float* __restrict__ Wt,
                                                  u16* __restrict__ u_hat) {
    const int g = blockIdx.x;             // 720 = 40 je-groups x 18 i-chunks
    const int jeg = g / 18;
    const int i = (g % 18) * 64 + threadIdx.x;
    float w[4][8];
#pragma unroll
    for (int q = 0; q < 4; ++q)
#pragma unroll
        for (int d = 0; d < 8; ++d)
            w[q][d] = Wt[((size_t)(jeg * 4 + q) * 8 + d) * 1152 + i];

    for (int b = 0; b < 512; ++b) {
        const float* up = ut + (size_t)b * 9216 + i;
        float u[8];
#pragma unroll
        for (int d = 0; d < 8; ++d) u[d] = up[(size_t)d * 1152];
#pragma unroll
        for (int q = 0; q < 4; ++q) {
            float acc = 0.f;
#pragma unroll
            for (int d = 0; d < 8; ++d) acc = fmaf(w[q][d], u[d], acc);
            u_hat[((size_t)b * 160 + jeg * 4 + q) * 1152 + i] = f2bf(acc);
        }
    }
}

// ---------- fused 5-iteration dynamic routing; b_log in registers, c in LDS ----------
__global__ __launch_bounds__(384) void routing_kernel(const u16* __restrict__ u_hat,
                                                      float* __restrict__ out) {
    __shared__ float cb[10 * 1152];       // c[j][i], 46 KB
    __shared__ float sv[160];             // s then v, [j*16+e]
    const int b = blockIdx.x;
    const int t = threadIdx.x;
    const u16* uh = u_hat + (size_t)b * 184320;

    float bl[3][10];                      // b_log for i = t, t+384, t+768
#pragma unroll
    for (int k = 0; k < 3; ++k)
#pragma unroll
        for (int j = 0; j < 10; ++j) bl[k][j] = 0.f;

    for (int it = 0; it < 5; ++it) {
        // softmax over j -> c
#pragma unroll
        for (int k = 0; k < 3; ++k) {
            const int i = t + 384 * k;
            float mx = bl[k][0];
#pragma unroll
            for (int j = 1; j < 10; ++j) mx = fmaxf(mx, bl[k][j]);
            float e[10], s = 0.f;
#pragma unroll
            for (int j = 0; j < 10; ++j) { e[j] = __expf(bl[k][j] - mx); s += e[j]; }
            const float inv = 1.f / s;
#pragma unroll
            for (int j = 0; j < 10; ++j) cb[j * 1152 + i] = e[j] * inv;
        }
        __syncthreads();

        // s[je] = sum_i c[j][i] * u_hat[je][i]
        if (t < 160) {
            const int j = t >> 4;
            const uint4* up = (const uint4*)(uh + (size_t)t * 1152);
            const float4* cp = (const float4*)(cb + j * 1152);
            float acc = 0.f;
            for (int i8 = 0; i8 < 144; ++i8) {
                uint4 u = up[i8];
                float4 c0 = cp[i8 * 2], c1 = cp[i8 * 2 + 1];
                acc += bflo(u.x) * c0.x + bfhi(u.x) * c0.y
                     + bflo(u.y) * c0.z + bfhi(u.y) * c0.w
                     + bflo(u.z) * c1.x + bfhi(u.z) * c1.y
                     + bflo(u.w) * c1.z + bfhi(u.w) * c1.w;
            }
            sv[t] = acc;
        }
        __syncthreads();

        // squash per j
        if (t < 10) {
            float n2 = 0.f;
#pragma unroll
            for (int e2 = 0; e2 < 16; ++e2) { float xx = sv[t * 16 + e2]; n2 += xx * xx; }
            float n = sqrtf(n2);
            float f = n / (n2 + 1.f);
#pragma unroll
            for (int e2 = 0; e2 < 16; ++e2) sv[t * 16 + e2] *= f;
        }
        __syncthreads();

        if (it == 4) break;

        // b_log += sum_e u_hat[j][e][i] * v[j][e]
#pragma unroll
        for (int k = 0; k < 3; ++k) {
            const int i = t + 384 * k;
#pragma unroll
            for (int j = 0; j < 10; ++j) {
                float acc = 0.f;
#pragma unroll
                for (int e2 = 0; e2 < 16; ++e2)
                    acc = fmaf(bf2f(uh[(size_t)(j * 16 + e2) * 1152 + i]), sv[j * 16 + e2], acc);
                bl[k][j] += acc;
            }
        }
        __syncthreads();
    }
    if (t < 160) out[(size_t)b * 160 + t] = sv[t];
}

extern "C" void kernel_launch(void* const* d_in, const int* in_sizes, int n_in,
                              void* d_out, int out_size, void* d_ws, size_t ws_size,
                              hipStream_t stream) {
    const float* x   = (const float*)d_in[0];
    const float* w1  = (const float*)d_in[1];
    const float* b1  = (const float*)d_in[2];
    const float* g1  = (const float*)d_in[3];
    const float* be1 = (const float*)d_in[4];
    const float* w2  = (const float*)d_in[5];
    const float* b2  = (const float*)d_in[6];
    const float* g2  = (const float*)d_in[7];
    const float* be2 = (const float*)d_in[8];
    const float* W   = (const float*)d_in[9];
    float* out = (float*)d_out;

    // ---- workspace layout (peak 213,524,480 B == round-1 proven-safe bound) ----
    // u_hat region [8K .. 188.75M) overlays y(bf16) + w2t(f32) + z(f32), all of
    // which are dead before uhat_kernel writes u_hat (stream-ordered).
    const size_t OFF_UHAT = 8192;                       // 188,743,680 B
    const size_t OFF_Y    = 8192;                       // 104,857,600 B (in u_hat region)
    const size_t OFF_W2T  = 104865792ull;               //  21,233,664 B (in u_hat region)
    const size_t OFF_Z    = 126099456ull;               //  18,874,368 B (in u_hat region)
    const size_t OFF_UT   = 188751872ull;               //  18,874,368 B
    const size_t OFF_WT   = 207626240ull;               //   5,898,240 B
    const size_t WS_NEED  = 213524480ull;
    if (ws_size < WS_NEED) return;  // diagnostic: clean absmax-fail instead of page fault

    char* ws = (char*)d_ws;
    float* sum1   = (float*)(ws + 0);
    float* sumsq1 = (float*)(ws + 1024);
    float* sum2   = (float*)(ws + 2048);
    float* sumsq2 = (float*)(ws + 3072);
    float* scale1 = (float*)(ws + 4096);
    float* shift1 = (float*)(ws + 5120);
    float* scale2 = (float*)(ws + 6144);
    float* shift2 = (float*)(ws + 7168);
    u16*   y_raw  = (u16*)(ws + OFF_Y);
    float* w2t    = (float*)(ws + OFF_W2T);
    float* z_raw  = (float*)(ws + OFF_Z);
    float* ut     = (float*)(ws + OFF_UT);
    float* Wt     = (float*)(ws + OFF_WT);
    u16*   u_hat  = (u16*)(ws + OFF_UHAT);

    hipMemsetAsync(ws, 0, 4096, stream);  // zero BN sum accumulators

    hipLaunchKernelGGL(repack_w2_kernel, dim3(20736), dim3(256), 0, stream, w2, w2t);
    hipLaunchKernelGGL(repack_W_kernel,  dim3(5760),  dim3(256), 0, stream, W, Wt);
    hipLaunchKernelGGL(conv1_kernel,     dim3(512),   dim3(256), 0, stream,
                       x, w1, b1, y_raw, sum1, sumsq1);
    hipLaunchKernelGGL(finalize_bn_kernel, dim3(1), dim3(256), 0, stream,
                       sum1, sumsq1, g1, be1, scale1, shift1, 1.f / 204800.f);
    hipLaunchKernelGGL(conv2_kernel,     dim3(512),   dim3(256), 0, stream,
                       y_raw, w2t, b2, scale1, shift1, z_raw, sum2, sumsq2);
    hipLaunchKernelGGL(finalize_bn_kernel, dim3(1), dim3(256), 0, stream,
                       sum2, sumsq2, g2, be2, scale2, shift2, 1.f / 18432.f);
    hipLaunchKernelGGL(ubuild_kernel,    dim3(512),   dim3(256), 0, stream,
                       z_raw, scale2, shift2, ut);
    hipLaunchKernelGGL(uhat_kernel,      dim3(720),   dim3(64),  0, stream, ut, Wt, u_hat);
    hipLaunchKernelGGL(routing_kernel,   dim3(512),   dim3(384), 0, stream, u_hat, out);
}

// Round 4
// 1904.729 us; speedup vs baseline: 2.4022x; 2.4022x over previous
//
#include <hip/hip_runtime.h>

typedef unsigned short u16;
typedef unsigned int   u32;
typedef __attribute__((ext_vector_type(8))) short bf16x8;  // 8 bf16 (4 VGPRs)
typedef __attribute__((ext_vector_type(4))) float f32x4;   // 4 fp32

// ---------- bf16 helpers (manual, RNE) ----------
__device__ __forceinline__ float bf2f(u16 u) { return __uint_as_float(((u32)u) << 16); }
__device__ __forceinline__ float bflo(u32 u) { return __uint_as_float(u << 16); }
__device__ __forceinline__ float bfhi(u32 u) { return __uint_as_float(u & 0xffff0000u); }
__device__ __forceinline__ u16 f2bf(float f) {
    u32 x = __float_as_uint(f);
    x += 0x7fffu + ((x >> 16) & 1u);   // round-to-nearest-even
    return (u16)(x >> 16);
}

// ---------- repack conv2 weights: w2r[kk][ccc][co][cil] bf16 ----------
// kk=kh*9+kw (81), ccc=ci/32 (8), co (256), cil=ci%32 (32)
__global__ __launch_bounds__(256) void repack_w2_kernel(const float* __restrict__ w2,
                                                        u16* __restrict__ w2r) {
    int idx = blockIdx.x * 256 + threadIdx.x;      // 81*8*256*32 = 5,308,416
    int cil = idx & 31;
    int co  = (idx >> 5) & 255;
    int ccc = (idx >> 13) & 7;
    int kk  = idx >> 16;
    int ci  = ccc * 32 + cil;
    w2r[idx] = f2bf(w2[(size_t)co * 20736 + (size_t)ci * 81 + kk]);
}

// ---------- repack W: Wt[je][d][i] f32 from W[j][i][d][e] ----------
__global__ __launch_bounds__(256) void repack_W_kernel(const float* __restrict__ W,
                                                       float* __restrict__ Wt) {
    int idx = blockIdx.x * 256 + threadIdx.x;      // total 10*16*8*1152 = 1474560
    int i = idx % 1152;
    int rest = idx / 1152;
    int d = rest & 7;
    int je = rest >> 3;
    int j = je >> 4, e = je & 15;
    Wt[idx] = W[(((size_t)j * 1152 + i) * 8 + d) * 16 + e];
}

// ---------- conv1 (9x9 s1) + bias + bf16 store [b][p][co] + BN1 stats ----------
__global__ __launch_bounds__(256) void conv1_kernel(const float* __restrict__ x,
                                                    const float* __restrict__ w1,
                                                    const float* __restrict__ b1,
                                                    u16* __restrict__ y,
                                                    float* __restrict__ sum1,
                                                    float* __restrict__ sumsq1) {
    __shared__ float xs[784];
    const int b = blockIdx.x;
    const int t = threadIdx.x;          // co
    const float* xb = x + (size_t)b * 784;
    for (int idx = t; idx < 784; idx += 256) xs[idx] = xb[idx];
    float w[81];
#pragma unroll
    for (int q = 0; q < 81; ++q) w[q] = w1[(size_t)t * 81 + q];
    const float bias = b1[t];
    __syncthreads();

    float sl = 0.f, ssl = 0.f;
    u16* yb = y + (size_t)b * 400 * 256 + t;     // channels-last, stride 256
    for (int oh = 0; oh < 20; ++oh) {
        float acc[20];
#pragma unroll
        for (int ow = 0; ow < 20; ++ow) acc[ow] = bias;
#pragma unroll
        for (int kh = 0; kh < 9; ++kh) {
            const float4* rp = (const float4*)(&xs[(oh + kh) * 28]);
            float r[28];
#pragma unroll
            for (int k4 = 0; k4 < 7; ++k4) {
                float4 f = rp[k4];
                r[k4 * 4 + 0] = f.x; r[k4 * 4 + 1] = f.y;
                r[k4 * 4 + 2] = f.z; r[k4 * 4 + 3] = f.w;
            }
#pragma unroll
            for (int kw = 0; kw < 9; ++kw) {
                const float wv = w[kh * 9 + kw];
#pragma unroll
                for (int ow = 0; ow < 20; ++ow)
                    acc[ow] = fmaf(wv, r[ow + kw], acc[ow]);
            }
        }
#pragma unroll
        for (int ow = 0; ow < 20; ++ow) {
            u16 q = f2bf(acc[ow]);
            float rv = bf2f(q);
            sl += rv; ssl += rv * rv;
            yb[(size_t)(oh * 20 + ow) * 256] = q;
        }
    }
    atomicAdd(&sum1[t], sl);
    atomicAdd(&sumsq1[t], ssl);
}

// ---------- BN finalize: scale/shift from sums ----------
__global__ void finalize_bn_kernel(const float* __restrict__ sum,
                                   const float* __restrict__ sumsq,
                                   const float* __restrict__ gam,
                                   const float* __restrict__ bet,
                                   float* __restrict__ scale,
                                   float* __restrict__ shift, float inv_n) {
    int c = threadIdx.x;
    float m = sum[c] * inv_n;
    float var = sumsq[c] * inv_n - m * m;
    float sc = gam[c] * rsqrtf(var + 1e-5f);
    scale[c] = sc;
    shift[c] = bet[c] - m * sc;
}

// ---------- BN1 + ReLU applied in-place on y [b][p][co] bf16 ----------
__global__ __launch_bounds__(256) void bnpack_kernel(u32* __restrict__ y32,
                                                     const float* __restrict__ scale1,
                                                     const float* __restrict__ shift1) {
    const int b = blockIdx.x;
    const int t = threadIdx.x;
    const int c2 = (t & 127) * 2;           // u32 column -> co pair (constant per thread)
    const float s0 = scale1[c2],     s1 = scale1[c2 + 1];
    const float h0 = shift1[c2],     h1 = shift1[c2 + 1];
    u32* base = y32 + (size_t)b * 51200;    // 400 pos * 128 u32
    for (int q = 0; q < 200; ++q) {
        const int idx = t + q * 256;
        u32 v = base[idx];
        float a = fmaxf(0.f, fmaf(s0, bflo(v), h0));
        float c = fmaxf(0.f, fmaf(s1, bfhi(v), h1));
        base[idx] = (u32)f2bf(a) | ((u32)f2bf(c) << 16);
    }
}

// ---------- conv2 as implicit-im2col bf16 MFMA GEMM ----------
// block = 1 image, 4 waves; wave w: co in [w*64, w*64+64), pos 0..47 (36 valid)
// K loop: 81 (kh,kw) x 8 ci-chunks of 32, mfma_f32_16x16x32_bf16
__global__ __launch_bounds__(256) void conv2_mfma_kernel(const u16* __restrict__ y,
                                                         const u16* __restrict__ w2r,
                                                         const float* __restrict__ b2,
                                                         float* __restrict__ z_raw,
                                                         float* __restrict__ sum2,
                                                         float* __restrict__ sumsq2) {
    __shared__ __align__(16) u16 patch[48 * 264];   // [pos(padded 48)][ci 256 + 8 pad]
    const int b = blockIdx.x;
    const int t = threadIdx.x;
    const int wave = t >> 6, lane = t & 63;
    const int n16 = lane & 15, quad = lane >> 4;

    f32x4 zero = {0.f, 0.f, 0.f, 0.f};
    f32x4 acc[4][3];
#pragma unroll
    for (int ct = 0; ct < 4; ++ct)
#pragma unroll
        for (int pt = 0; pt < 3; ++pt) acc[ct][pt] = zero;

    const u16* yb = y + (size_t)b * 400 * 256;

    for (int kk = 0; kk < 81; ++kk) {
        const int kh = kk / 9, kw = kk - kh * 9;
        __syncthreads();
        // stage 36 rows x 512B (gathered strided rows, contiguous within row)
        for (int v = t; v < 36 * 32; v += 256) {
            const int r = v >> 5, ch = v & 31;
            const int oh = r / 6, ow = r - oh * 6;
            const int ip = (2 * oh + kh) * 20 + (2 * ow + kw);
            const uint4 d = ((const uint4*)(yb + (size_t)ip * 256))[ch];
            *((uint4*)(patch + r * 264 + ch * 8)) = d;
        }
        __syncthreads();

        const u16* wk = w2r + (size_t)kk * 65536;
#pragma unroll 2
        for (int ccc = 0; ccc < 8; ++ccc) {
            bf16x8 afr[4];
            const u16* wa = wk + (size_t)ccc * 8192 + (wave * 64 + n16) * 32 + quad * 8;
#pragma unroll
            for (int ct = 0; ct < 4; ++ct)
                afr[ct] = *((const bf16x8*)(wa + ct * 512));       // 16 co * 32
            bf16x8 bfr[3];
            const u16* pb = patch + n16 * 264 + ccc * 32 + quad * 8;
#pragma unroll
            for (int pt = 0; pt < 3; ++pt)
                bfr[pt] = *((const bf16x8*)(pb + pt * 4224));      // 16 pos * 264
#pragma unroll
            for (int ct = 0; ct < 4; ++ct)
#pragma unroll
                for (int pt = 0; pt < 3; ++pt)
                    acc[ct][pt] = __builtin_amdgcn_mfma_f32_16x16x32_bf16(
                        afr[ct], bfr[pt], acc[ct][pt], 0, 0, 0);
        }
    }

    // epilogue: bias, store z[b][co][36], BN2 stats (shfl-reduce over n16)
    const int co0 = wave * 64 + quad * 4;
#pragma unroll
    for (int ct = 0; ct < 4; ++ct) {
#pragma unroll
        for (int r = 0; r < 4; ++r) {
            const int co = co0 + ct * 16 + r;
            const float bias = b2[co];
            float s = 0.f, ss = 0.f;
#pragma unroll
            for (int pt = 0; pt < 3; ++pt) {
                const int pos = pt * 16 + n16;
                if (pos < 36) {
                    float v = acc[ct][pt][r] + bias;
                    z_raw[((size_t)b * 256 + co) * 36 + pos] = v;
                    s += v; ss += v * v;
                }
            }
#pragma unroll
            for (int m = 1; m < 16; m <<= 1) {
                s  += __shfl_xor(s,  m, 64);
                ss += __shfl_xor(ss, m, 64);
            }
            if (n16 == 0) { atomicAdd(&sum2[co], s); atomicAdd(&sumsq2[co], ss); }
        }
    }
}

// ---------- BN2 + ReLU + capsule transpose: ut[b][d][i] f32, i = m*36+s, c = d*32+m ----------
__global__ __launch_bounds__(256) void ubuild_kernel(const float* __restrict__ z_raw,
                                                     const float* __restrict__ scale2,
                                                     const float* __restrict__ shift2,
                                                     float* __restrict__ ut) {
    const int b = blockIdx.x;
    const int t = threadIdx.x;            // c
    const int d = t >> 5, m = t & 31;
    const float sc = scale2[t], sh = shift2[t];
    const float4* zp = (const float4*)(z_raw + ((size_t)b * 256 + t) * 36);
    float4* up = (float4*)(ut + ((size_t)b * 8 + d) * 1152 + m * 36);
#pragma unroll
    for (int q = 0; q < 9; ++q) {
        float4 z = zp[q];
        float4 o;
        o.x = fmaxf(0.f, fmaf(sc, z.x, sh));
        o.y = fmaxf(0.f, fmaf(sc, z.y, sh));
        o.z = fmaxf(0.f, fmaf(sc, z.z, sh));
        o.w = fmaxf(0.f, fmaf(sc, z.w, sh));
        up[q] = o;
    }
}

// ---------- u_hat[b][je][i] bf16 = sum_d ut[b][d][i] * Wt[je][d][i] ----------
__global__ __launch_bounds__(64) void uhat_kernel(const float* __restrict__ ut,
                                                  const float* __restrict__ Wt,
                                                  u16* __restrict__ u_hat) {
    const int g = blockIdx.x;             // 720 = 40 je-groups x 18 i-chunks
    const int jeg = g / 18;
    const int i = (g % 18) * 64 + threadIdx.x;
    float w[4][8];
#pragma unroll
    for (int q = 0; q < 4; ++q)
#pragma unroll
        for (int d = 0; d < 8; ++d)
            w[q][d] = Wt[((size_t)(jeg * 4 + q) * 8 + d) * 1152 + i];

    for (int b = 0; b < 512; ++b) {
        const float* up = ut + (size_t)b * 9216 + i;
        float u[8];
#pragma unroll
        for (int d = 0; d < 8; ++d) u[d] = up[(size_t)d * 1152];
#pragma unroll
        for (int q = 0; q < 4; ++q) {
            float acc = 0.f;
#pragma unroll
            for (int d = 0; d < 8; ++d) acc = fmaf(w[q][d], u[d], acc);
            u_hat[((size_t)b * 160 + jeg * 4 + q) * 1152 + i] = f2bf(acc);
        }
    }
}

// ---------- fused 5-iteration dynamic routing ----------
__global__ __launch_bounds__(384) void routing_kernel(const u16* __restrict__ u_hat,
                                                      float* __restrict__ out) {
    __shared__ float cb[10 * 1152];       // c[j][i], 46 KB
    __shared__ float part[320];           // s partial sums
    __shared__ float sv[160];             // s then v, [j*16+e]
    const int b = blockIdx.x;
    const int t = threadIdx.x;
    const u16* uh = u_hat + (size_t)b * 184320;

    float bl[3][10];                      // b_log for i = t, t+384, t+768
#pragma unroll
    for (int k = 0; k < 3; ++k)
#pragma unroll
        for (int j = 0; j < 10; ++j) bl[k][j] = 0.f;

    for (int it = 0; it < 5; ++it) {
        // softmax over j -> c
#pragma unroll
        for (int k = 0; k < 3; ++k) {
            const int i = t + 384 * k;
            float mx = bl[k][0];
#pragma unroll
            for (int j = 1; j < 10; ++j) mx = fmaxf(mx, bl[k][j]);
            float e[10], s = 0.f;
#pragma unroll
            for (int j = 0; j < 10; ++j) { e[j] = __expf(bl[k][j] - mx); s += e[j]; }
            const float inv = 1.f / s;
#pragma unroll
            for (int j = 0; j < 10; ++j) cb[j * 1152 + i] = e[j] * inv;
        }
        __syncthreads();

        // s[je] = sum_i c[j][i] * u_hat[je][i] -- 320 workers, 2 halves of i
        if (t < 320) {
            const int h  = (t >= 160) ? 1 : 0;
            const int je = t - h * 160;
            const int j  = je >> 4;
            const uint4* up  = (const uint4*)(uh + (size_t)je * 1152) + h * 72;
            const float4* cp = (const float4*)(cb + (size_t)j * 1152) + h * 144;
            float a0 = 0.f, a1 = 0.f;
            for (int i8 = 0; i8 < 72; i8 += 2) {
                uint4 u = up[i8];
                float4 c0 = cp[2 * i8], c1 = cp[2 * i8 + 1];
                a0 += bflo(u.x) * c0.x + bfhi(u.x) * c0.y
                    + bflo(u.y) * c0.z + bfhi(u.y) * c0.w
                    + bflo(u.z) * c1.x + bfhi(u.z) * c1.y
                    + bflo(u.w) * c1.z + bfhi(u.w) * c1.w;
                uint4 u2 = up[i8 + 1];
                float4 c2 = cp[2 * i8 + 2], c3 = cp[2 * i8 + 3];
                a1 += bflo(u2.x) * c2.x + bfhi(u2.x) * c2.y
                    + bflo(u2.y) * c2.z + bfhi(u2.y) * c2.w
                    + bflo(u2.z) * c3.x + bfhi(u2.z) * c3.y
                    + bflo(u2.w) * c3.z + bfhi(u2.w) * c3.w;
            }
            part[t] = a0 + a1;
        }
        __syncthreads();
        if (t < 160) sv[t] = part[t] + part[t + 160];
        __syncthreads();

        // squash per j
        if (t < 10) {
            float n2 = 0.f;
#pragma unroll
            for (int e2 = 0; e2 < 16; ++e2) { float xx = sv[t * 16 + e2]; n2 += xx * xx; }
            float n = sqrtf(n2);
            float f = n / (n2 + 1.f);
#pragma unroll
            for (int e2 = 0; e2 < 16; ++e2) sv[t * 16 + e2] *= f;
        }
        __syncthreads();

        if (it == 4) break;

        // b_log += sum_e u_hat[j][e][i] * v[j][e]
#pragma unroll
        for (int k = 0; k < 3; ++k) {
            const int i = t + 384 * k;
#pragma unroll
            for (int j = 0; j < 10; ++j) {
                float acc = 0.f;
#pragma unroll
                for (int e2 = 0; e2 < 16; ++e2)
                    acc = fmaf(bf2f(uh[(size_t)(j * 16 + e2) * 1152 + i]), sv[j * 16 + e2], acc);
                bl[k][j] += acc;
            }
        }
        __syncthreads();
    }
    if (t < 160) out[(size_t)b * 160 + t] = sv[t];
}

extern "C" void kernel_launch(void* const* d_in, const int* in_sizes, int n_in,
                              void* d_out, int out_size, void* d_ws, size_t ws_size,
                              hipStream_t stream) {
    const float* x   = (const float*)d_in[0];
    const float* w1  = (const float*)d_in[1];
    const float* b1  = (const float*)d_in[2];
    const float* g1  = (const float*)d_in[3];
    const float* be1 = (const float*)d_in[4];
    const float* w2  = (const float*)d_in[5];
    const float* b2  = (const float*)d_in[6];
    const float* g2  = (const float*)d_in[7];
    const float* be2 = (const float*)d_in[8];
    const float* W   = (const float*)d_in[9];
    float* out = (float*)d_out;

    // ---- workspace layout (peak 213,524,480 B == proven-safe bound) ----
    // u_hat region [8K .. 188.75M) overlays y(bf16,in-place BN) + w2r(bf16) + z(f32),
    // all dead before uhat_kernel writes u_hat (stream-ordered).
    const size_t OFF_UHAT = 8192;                       // 188,743,680 B
    const size_t OFF_Y    = 8192;                       // 104,857,600 B (in u_hat region)
    const size_t OFF_W2R  = 104865792ull;               //  10,616,832 B (in u_hat region)
    const size_t OFF_Z    = 126099456ull;               //  18,874,368 B (in u_hat region)
    const size_t OFF_UT   = 188751872ull;               //  18,874,368 B
    const size_t OFF_WT   = 207626240ull;               //   5,898,240 B
    const size_t WS_NEED  = 213524480ull;
    if (ws_size < WS_NEED) return;  // diagnostic: clean absmax-fail instead of page fault

    char* ws = (char*)d_ws;
    float* sum1   = (float*)(ws + 0);
    float* sumsq1 = (float*)(ws + 1024);
    float* sum2   = (float*)(ws + 2048);
    float* sumsq2 = (float*)(ws + 3072);
    float* scale1 = (float*)(ws + 4096);
    float* shift1 = (float*)(ws + 5120);
    float* scale2 = (float*)(ws + 6144);
    float* shift2 = (float*)(ws + 7168);
    u16*   y     = (u16*)(ws + OFF_Y);
    u16*   w2r   = (u16*)(ws + OFF_W2R);
    float* z_raw = (float*)(ws + OFF_Z);
    float* ut    = (float*)(ws + OFF_UT);
    float* Wt    = (float*)(ws + OFF_WT);
    u16*   u_hat = (u16*)(ws + OFF_UHAT);

    hipMemsetAsync(ws, 0, 4096, stream);  // zero BN sum accumulators

    hipLaunchKernelGGL(repack_w2_kernel, dim3(20736), dim3(256), 0, stream, w2, w2r);
    hipLaunchKernelGGL(repack_W_kernel,  dim3(5760),  dim3(256), 0, stream, W, Wt);
    hipLaunchKernelGGL(conv1_kernel,     dim3(512),   dim3(256), 0, stream,
                       x, w1, b1, y, sum1, sumsq1);
    hipLaunchKernelGGL(finalize_bn_kernel, dim3(1), dim3(256), 0, stream,
                       sum1, sumsq1, g1, be1, scale1, shift1, 1.f / 204800.f);
    hipLaunchKernelGGL(bnpack_kernel,    dim3(512),   dim3(256), 0, stream,
                       (u32*)y, scale1, shift1);
    hipLaunchKernelGGL(conv2_mfma_kernel, dim3(512),  dim3(256), 0, stream,
                       y, w2r, b2, z_raw, sum2, sumsq2);
    hipLaunchKernelGGL(finalize_bn_kernel, dim3(1), dim3(256), 0, stream,
                       sum2, sumsq2, g2, be2, scale2, shift2, 1.f / 18432.f);
    hipLaunchKernelGGL(ubuild_kernel,    dim3(512),   dim3(256), 0, stream,
                       z_raw, scale2, shift2, ut);
    hipLaunchKernelGGL(uhat_kernel,      dim3(720),   dim3(64),  0, stream, ut, Wt, u_hat);
    hipLaunchKernelGGL(routing_kernel,   dim3(512),   dim3(384), 0, stream, u_hat, out);
}

// Round 5
// 1601.299 us; speedup vs baseline: 2.8573x; 1.1895x over previous
//
#include <hip/hip_runtime.h>

typedef unsigned short u16;
typedef unsigned int   u32;
typedef __attribute__((ext_vector_type(8))) short bf16x8;  // 8 bf16 (4 VGPRs)
typedef __attribute__((ext_vector_type(4))) float f32x4;   // 4 fp32

// ---------- bf16 helpers (manual, RNE) ----------
__device__ __forceinline__ float bf2f(u16 u) { return __uint_as_float(((u32)u) << 16); }
__device__ __forceinline__ float bflo(u32 u) { return __uint_as_float(u << 16); }
__device__ __forceinline__ float bfhi(u32 u) { return __uint_as_float(u & 0xffff0000u); }
__device__ __forceinline__ u16 f2bf(float f) {
    u32 x = __float_as_uint(f);
    x += 0x7fffu + ((x >> 16) & 1u);   // round-to-nearest-even
    return (u16)(x >> 16);
}

// ---------- repack conv2 weights: w2r[kk][ccc][h][co][cil], h=0 hi plane, h=1 lo plane ----------
// error-compensated bf16: w ~= hi + lo, two MFMAs per chunk recover ~fp32 weight precision
__global__ __launch_bounds__(256) void repack_w2_kernel(const float* __restrict__ w2,
                                                        u16* __restrict__ w2r) {
    int idx = blockIdx.x * 256 + threadIdx.x;      // 81*8*2*256*32 = 10,616,832
    int cil = idx & 31;
    int co  = (idx >> 5) & 255;
    int h   = (idx >> 13) & 1;
    int ccc = (idx >> 14) & 7;
    int kk  = idx >> 17;
    int ci  = ccc * 32 + cil;
    float v = w2[(size_t)co * 20736 + (size_t)ci * 81 + kk];
    u16 hi = f2bf(v);
    w2r[idx] = h ? f2bf(v - bf2f(hi)) : hi;
}

// ---------- repack W: Wt2[i][je][d] f32 from W[j][i][d][e] ----------
__global__ __launch_bounds__(256) void repack_W_kernel(const float* __restrict__ W,
                                                       float* __restrict__ Wt2) {
    int idx = blockIdx.x * 256 + threadIdx.x;      // total 1152*160*8 = 1,474,560
    int d  = idx & 7;
    int je = (idx >> 3) % 160;
    int i  = idx / 1280;
    int j = je >> 4, e = je & 15;
    Wt2[idx] = W[(((size_t)j * 1152 + i) * 8 + d) * 16 + e];
}

// ---------- conv1 (9x9 s1) + bias + bf16 store [b][p][co] + BN1 stats ----------
__global__ __launch_bounds__(256) void conv1_kernel(const float* __restrict__ x,
                                                    const float* __restrict__ w1,
                                                    const float* __restrict__ b1,
                                                    u16* __restrict__ y,
                                                    float* __restrict__ sum1,
                                                    float* __restrict__ sumsq1) {
    __shared__ float xs[784];
    const int b = blockIdx.x;
    const int t = threadIdx.x;          // co
    const float* xb = x + (size_t)b * 784;
    for (int idx = t; idx < 784; idx += 256) xs[idx] = xb[idx];
    float w[81];
#pragma unroll
    for (int q = 0; q < 81; ++q) w[q] = w1[(size_t)t * 81 + q];
    const float bias = b1[t];
    __syncthreads();

    float sl = 0.f, ssl = 0.f;
    u16* yb = y + (size_t)b * 400 * 256 + t;     // channels-last, stride 256
    for (int oh = 0; oh < 20; ++oh) {
        float acc[20];
#pragma unroll
        for (int ow = 0; ow < 20; ++ow) acc[ow] = bias;
#pragma unroll
        for (int kh = 0; kh < 9; ++kh) {
            const float4* rp = (const float4*)(&xs[(oh + kh) * 28]);
            float r[28];
#pragma unroll
            for (int k4 = 0; k4 < 7; ++k4) {
                float4 f = rp[k4];
                r[k4 * 4 + 0] = f.x; r[k4 * 4 + 1] = f.y;
                r[k4 * 4 + 2] = f.z; r[k4 * 4 + 3] = f.w;
            }
#pragma unroll
            for (int kw = 0; kw < 9; ++kw) {
                const float wv = w[kh * 9 + kw];
#pragma unroll
                for (int ow = 0; ow < 20; ++ow)
                    acc[ow] = fmaf(wv, r[ow + kw], acc[ow]);
            }
        }
#pragma unroll
        for (int ow = 0; ow < 20; ++ow) {
            u16 q = f2bf(acc[ow]);
            float rv = bf2f(q);
            sl += rv; ssl += rv * rv;
            yb[(size_t)(oh * 20 + ow) * 256] = q;
        }
    }
    atomicAdd(&sum1[t], sl);
    atomicAdd(&sumsq1[t], ssl);
}

// ---------- BN finalize: scale/shift from sums ----------
__global__ void finalize_bn_kernel(const float* __restrict__ sum,
                                   const float* __restrict__ sumsq,
                                   const float* __restrict__ gam,
                                   const float* __restrict__ bet,
                                   float* __restrict__ scale,
                                   float* __restrict__ shift, float inv_n) {
    int c = threadIdx.x;
    float m = sum[c] * inv_n;
    float var = sumsq[c] * inv_n - m * m;
    float sc = gam[c] * rsqrtf(var + 1e-5f);
    scale[c] = sc;
    shift[c] = bet[c] - m * sc;
}

// ---------- BN1 + ReLU applied in-place on y [b][p][co] bf16 ----------
__global__ __launch_bounds__(256) void bnpack_kernel(u32* __restrict__ y32,
                                                     const float* __restrict__ scale1,
                                                     const float* __restrict__ shift1) {
    const int b = blockIdx.x;
    const int t = threadIdx.x;
    const int c2 = (t & 127) * 2;           // u32 column -> co pair (constant per thread)
    const float s0 = scale1[c2],     s1 = scale1[c2 + 1];
    const float h0 = shift1[c2],     h1 = shift1[c2 + 1];
    u32* base = y32 + (size_t)b * 51200;    // 400 pos * 128 u32
    for (int q = 0; q < 200; ++q) {
        const int idx = t + q * 256;
        u32 v = base[idx];
        float a = fmaxf(0.f, fmaf(s0, bflo(v), h0));
        float c = fmaxf(0.f, fmaf(s1, bfhi(v), h1));
        base[idx] = (u32)f2bf(a) | ((u32)f2bf(c) << 16);
    }
}

// ---------- conv2 as implicit-im2col bf16 MFMA GEMM (hi+lo compensated weights) ----------
__global__ __launch_bounds__(256) void conv2_mfma_kernel(const u16* __restrict__ y,
                                                         const u16* __restrict__ w2r,
                                                         const float* __restrict__ b2,
                                                         float* __restrict__ z_raw,
                                                         float* __restrict__ sum2,
                                                         float* __restrict__ sumsq2) {
    __shared__ __align__(16) u16 patch[48 * 264];   // [pos(padded 48)][ci 256 + 8 pad]
    const int b = blockIdx.x;
    const int t = threadIdx.x;
    const int wave = t >> 6, lane = t & 63;
    const int n16 = lane & 15, quad = lane >> 4;

    f32x4 zero = {0.f, 0.f, 0.f, 0.f};
    f32x4 acc[4][3];
#pragma unroll
    for (int ct = 0; ct < 4; ++ct)
#pragma unroll
        for (int pt = 0; pt < 3; ++pt) acc[ct][pt] = zero;

    const u16* yb = y + (size_t)b * 400 * 256;

    for (int kk = 0; kk < 81; ++kk) {
        const int kh = kk / 9, kw = kk - kh * 9;
        __syncthreads();
        for (int v = t; v < 36 * 32; v += 256) {
            const int r = v >> 5, ch = v & 31;
            const int oh = r / 6, ow = r - oh * 6;
            const int ip = (2 * oh + kh) * 20 + (2 * ow + kw);
            const uint4 d = ((const uint4*)(yb + (size_t)ip * 256))[ch];
            *((uint4*)(patch + r * 264 + ch * 8)) = d;
        }
        __syncthreads();

        const u16* wk = w2r + (size_t)kk * 131072;
#pragma unroll 2
        for (int ccc = 0; ccc < 8; ++ccc) {
            bf16x8 ah[4], al[4];
            const u16* wa = wk + ccc * 16384 + (wave * 64 + n16) * 32 + quad * 8;
#pragma unroll
            for (int ct = 0; ct < 4; ++ct) {
                ah[ct] = *((const bf16x8*)(wa + ct * 512));
                al[ct] = *((const bf16x8*)(wa + 8192 + ct * 512));
            }
            bf16x8 bfr[3];
            const u16* pb = patch + n16 * 264 + ccc * 32 + quad * 8;
#pragma unroll
            for (int pt = 0; pt < 3; ++pt)
                bfr[pt] = *((const bf16x8*)(pb + pt * 4224));
#pragma unroll
            for (int ct = 0; ct < 4; ++ct)
#pragma unroll
                for (int pt = 0; pt < 3; ++pt) {
                    acc[ct][pt] = __builtin_amdgcn_mfma_f32_16x16x32_bf16(
                        ah[ct], bfr[pt], acc[ct][pt], 0, 0, 0);
                    acc[ct][pt] = __builtin_amdgcn_mfma_f32_16x16x32_bf16(
                        al[ct], bfr[pt], acc[ct][pt], 0, 0, 0);
                }
        }
    }

    const int co0 = wave * 64 + quad * 4;
#pragma unroll
    for (int ct = 0; ct < 4; ++ct) {
#pragma unroll
        for (int r = 0; r < 4; ++r) {
            const int co = co0 + ct * 16 + r;
            const float bias = b2[co];
            float s = 0.f, ss = 0.f;
#pragma unroll
            for (int pt = 0; pt < 3; ++pt) {
                const int pos = pt * 16 + n16;
                if (pos < 36) {
                    float v = acc[ct][pt][r] + bias;
                    z_raw[((size_t)b * 256 + co) * 36 + pos] = v;
                    s += v; ss += v * v;
                }
            }
#pragma unroll
            for (int m = 1; m < 16; m <<= 1) {
                s  += __shfl_xor(s,  m, 64);
                ss += __shfl_xor(ss, m, 64);
            }
            if (n16 == 0) { atomicAdd(&sum2[co], s); atomicAdd(&sumsq2[co], ss); }
        }
    }
}

// ---------- BN2 + ReLU + capsule transpose: ut[b][d][i] f32, i = m*36+s, c = d*32+m ----------
__global__ __launch_bounds__(256) void ubuild_kernel(const float* __restrict__ z_raw,
                                                     const float* __restrict__ scale2,
                                                     const float* __restrict__ shift2,
                                                     float* __restrict__ ut) {
    const int b = blockIdx.x;
    const int t = threadIdx.x;            // c
    const int d = t >> 5, m = t & 31;
    const float sc = scale2[t], sh = shift2[t];
    const float4* zp = (const float4*)(z_raw + ((size_t)b * 256 + t) * 36);
    float4* up = (float4*)(ut + ((size_t)b * 8 + d) * 1152 + m * 36);
#pragma unroll
    for (int q = 0; q < 9; ++q) {
        float4 z = zp[q];
        float4 o;
        o.x = fmaxf(0.f, fmaf(sc, z.x, sh));
        o.y = fmaxf(0.f, fmaf(sc, z.y, sh));
        o.z = fmaxf(0.f, fmaf(sc, z.z, sh));
        o.w = fmaxf(0.f, fmaf(sc, z.w, sh));
        up[q] = o;
    }
}

// ---------- u_hat[b][i][je] bf16 = sum_d ut[b][d][i] * Wt2[i][je][d] ----------
// block: 8 images x 144-i chunk; W fragment held in regs across the 8-image loop
__global__ __launch_bounds__(256) void uhat_kernel(const float* __restrict__ ut,
                                                   const float* __restrict__ Wt2,
                                                   u16* __restrict__ u_hat) {
    __shared__ float utl[8 * 8 * 144];    // [bb][d][ii], 36 KB
    const int bg = blockIdx.x >> 3;       // 64 image-groups of 8
    const int ic = blockIdx.x & 7;        // 8 i-chunks of 144
    const int b0 = bg * 8, i0 = ic * 144;
    for (int v = threadIdx.x; v < 8 * 8 * 144; v += 256) {
        int ii = v % 144; int d = (v / 144) & 7; int bb = v / 1152;
        utl[v] = ut[(size_t)(b0 + bb) * 9216 + d * 1152 + i0 + ii];
    }
    __syncthreads();
    for (int q = 0; q < 90; ++q) {
        int o = q * 256 + threadIdx.x;    // 144*160 = 23040 = 90*256
        int ii = o / 160, je = o - ii * 160;
        const float* wp = Wt2 + ((size_t)(i0 + ii) * 160 + je) * 8;
        float w[8];
#pragma unroll
        for (int d = 0; d < 8; ++d) w[d] = wp[d];
#pragma unroll
        for (int bb = 0; bb < 8; ++bb) {
            float acc = 0.f;
#pragma unroll
            for (int d = 0; d < 8; ++d) acc = fmaf(w[d], utl[bb * 1152 + d * 144 + ii], acc);
            u_hat[(size_t)(b0 + bb) * 184320 + (size_t)(i0 + ii) * 160 + je] = f2bf(acc);
        }
    }
}

// ---------- fused 5-iteration routing: ONE u_hat pass per iteration ----------
// u_hat[b][i][je]; per block: 6 chunks of 192 i staged to LDS;
// phase A (per-i): b_log += u.v_prev, softmax -> c ; phase B (per-je): s += c*u
__global__ __launch_bounds__(384) void routing_kernel(const u16* __restrict__ u_hat,
                                                      float* __restrict__ out) {
    __shared__ __align__(16) u16 uhs[192 * 164];  // 192 rows x (320B data + 8B pad)
    __shared__ float cl[10 * 192];                // c[j][i_local]
    __shared__ float blg[10 * 192 * 6 / 6];       // placeholder comment; real decl below
    __shared__ float part[320];
    __shared__ float sv[160];                     // s then v
    const int b = blockIdx.x;
    const int t = threadIdx.x;
    const u16* uh = u_hat + (size_t)b * 184320;
    const int half = (t < 320) ? (t >> 7) - ((t >> 7) == 2 ? 1 : 0) : 0;  // not used; real below
    (void)half;
    const int hB = (t < 320) ? (t / 160) : 0;
    const int je = (t < 320) ? (t - hB * 160) : 0;
    const int jB = je >> 4;

    // b_log[j][i] lives in a second LDS array (full i range): 10*1152 won't fit;
    // instead b_log[j][i_local] is per-chunk -> must persist across iterations:
    // store b_log for ALL i: use cl-style per-chunk slices held in a dedicated array
    __shared__ float blog[10 * 1152 / 6];         // 10 x 192 per chunk? NO -- see below
    (void)blog;

    // ---- b_log for all 1152 i, 10 j: 45 KB does not fit with uhs; instead
    // keep b_log per chunk in uhs-independent array indexed by chunk via regs:
    // threads t<192 own i = c*192+t for each chunk c -> bl[6][10] in registers.
    float bl[6][10];
#pragma unroll
    for (int c = 0; c < 6; ++c)
#pragma unroll
        for (int j = 0; j < 10; ++j) bl[c][j] = 0.f;

    for (int k = 0; k < 5; ++k) {
        float sacc = 0.f;
        for (int c = 0; c < 6; ++c) {
            __syncthreads();               // uhs free (prev chunk's B / prev iter done)
            const u16* src = uh + (size_t)c * 30720;   // 192*160
#pragma unroll
            for (int q = 0; q < 20; ++q) {
                int v = t + q * 384;       // < 7680
                int r = v / 40, off = v - r * 40;
                uint2 d = *((const uint2*)(src + r * 160 + off * 4));
                *((uint2*)(uhs + r * 164 + off * 4)) = d;
            }
            __syncthreads();
            if (k > 0 && t < 192) {        // phase A
                const u16* row = uhs + t * 164;
                float bj[10];
#pragma unroll
                for (int j = 0; j < 10; ++j) {
                    float dj = 0.f;
#pragma unroll
                    for (int q = 0; q < 4; ++q) {
                        uint2 v2 = *((const uint2*)(row + j * 16 + q * 4));
                        dj += bflo(v2.x) * sv[j * 16 + q * 4]
                            + bfhi(v2.x) * sv[j * 16 + q * 4 + 1]
                            + bflo(v2.y) * sv[j * 16 + q * 4 + 2]
                            + bfhi(v2.y) * sv[j * 16 + q * 4 + 3];
                    }
                    bl[c][j] += dj;
                    bj[j] = bl[c][j];
                }
                float mx = bj[0];
#pragma unroll
                for (int j = 1; j < 10; ++j) mx = fmaxf(mx, bj[j]);
                float s = 0.f;
#pragma unroll
                for (int j = 0; j < 10; ++j) { bj[j] = __expf(bj[j] - mx); s += bj[j]; }
                float inv = 1.f / s;
#pragma unroll
                for (int j = 0; j < 10; ++j) cl[j * 192 + t] = bj[j] * inv;
            }
            __syncthreads();
            if (t < 320) {                 // phase B
                const int r0 = hB * 96;
                if (k == 0) {
                    float a = 0.f;
#pragma unroll 4
                    for (int il = 0; il < 96; ++il)
                        a += bf2f(uhs[(r0 + il) * 164 + je]);
                    sacc = fmaf(0.1f, a, sacc);
                } else {
#pragma unroll 4
                    for (int il = 0; il < 96; ++il) {
                        const int r = r0 + il;
                        sacc = fmaf(cl[jB * 192 + r], bf2f(uhs[r * 164 + je]), sacc);
                    }
                }
            }
        }
        __syncthreads();
        if (t < 320) part[t] = sacc;
        __syncthreads();
        if (t < 160) sv[t] = part[t] + part[t + 160];
        __syncthreads();
        if (t < 10) {
            float n2 = 0.f;
#pragma unroll
            for (int e2 = 0; e2 < 16; ++e2) { float xx = sv[t * 16 + e2]; n2 += xx * xx; }
            float n = sqrtf(n2);
            float f = n / (n2 + 1.f);
#pragma unroll
            for (int e2 = 0; e2 < 16; ++e2) sv[t * 16 + e2] *= f;
        }
        __syncthreads();
    }
    if (t < 160) out[(size_t)b * 160 + t] = sv[t];
}

extern "C" void kernel_launch(void* const* d_in, const int* in_sizes, int n_in,
                              void* d_out, int out_size, void* d_ws, size_t ws_size,
                              hipStream_t stream) {
    const float* x   = (const float*)d_in[0];
    const float* w1  = (const float*)d_in[1];
    const float* b1  = (const float*)d_in[2];
    const float* g1  = (const float*)d_in[3];
    const float* be1 = (const float*)d_in[4];
    const float* w2  = (const float*)d_in[5];
    const float* b2  = (const float*)d_in[6];
    const float* g2  = (const float*)d_in[7];
    const float* be2 = (const float*)d_in[8];
    const float* W   = (const float*)d_in[9];
    float* out = (float*)d_out;

    // ---- workspace layout (peak 213,524,480 B == proven-safe bound) ----
    // u_hat region [8K .. 188.75M) overlays y + w2r(hi/lo, 21.2MB) + z, all dead
    // before uhat_kernel writes u_hat (stream-ordered).
    const size_t OFF_UHAT = 8192;                       // 188,743,680 B
    const size_t OFF_Y    = 8192;                       // 104,857,600 B (in u_hat region)
    const size_t OFF_W2R  = 104865792ull;               //  21,233,664 B (in u_hat region)
    const size_t OFF_Z    = 126099456ull;               //  18,874,368 B (in u_hat region)
    const size_t OFF_UT   = 188751872ull;               //  18,874,368 B
    const size_t OFF_WT   = 207626240ull;               //   5,898,240 B
    const size_t WS_NEED  = 213524480ull;
    if (ws_size < WS_NEED) return;  // diagnostic: clean absmax-fail instead of page fault

    char* ws = (char*)d_ws;
    float* sum1   = (float*)(ws + 0);
    float* sumsq1 = (float*)(ws + 1024);
    float* sum2   = (float*)(ws + 2048);
    float* sumsq2 = (float*)(ws + 3072);
    float* scale1 = (float*)(ws + 4096);
    float* shift1 = (float*)(ws + 5120);
    float* scale2 = (float*)(ws + 6144);
    float* shift2 = (float*)(ws + 7168);
    u16*   y     = (u16*)(ws + OFF_Y);
    u16*   w2r   = (u16*)(ws + OFF_W2R);
    float* z_raw = (float*)(ws + OFF_Z);
    float* ut    = (float*)(ws + OFF_UT);
    float* Wt2   = (float*)(ws + OFF_WT);
    u16*   u_hat = (u16*)(ws + OFF_UHAT);

    hipMemsetAsync(ws, 0, 4096, stream);  // zero BN sum accumulators

    hipLaunchKernelGGL(repack_w2_kernel, dim3(41472), dim3(256), 0, stream, w2, w2r);
    hipLaunchKernelGGL(repack_W_kernel,  dim3(5760),  dim3(256), 0, stream, W, Wt2);
    hipLaunchKernelGGL(conv1_kernel,     dim3(512),   dim3(256), 0, stream,
                       x, w1, b1, y, sum1, sumsq1);
    hipLaunchKernelGGL(finalize_bn_kernel, dim3(1), dim3(256), 0, stream,
                       sum1, sumsq1, g1, be1, scale1, shift1, 1.f / 204800.f);
    hipLaunchKernelGGL(bnpack_kernel,    dim3(512),   dim3(256), 0, stream,
                       (u32*)y, scale1, shift1);
    hipLaunchKernelGGL(conv2_mfma_kernel, dim3(512),  dim3(256), 0, stream,
                       y, w2r, b2, z_raw, sum2, sumsq2);
    hipLaunchKernelGGL(finalize_bn_kernel, dim3(1), dim3(256), 0, stream,
                       sum2, sumsq2, g2, be2, scale2, shift2, 1.f / 18432.f);
    hipLaunchKernelGGL(ubuild_kernel,    dim3(512),   dim3(256), 0, stream,
                       z_raw, scale2, shift2, ut);
    hipLaunchKernelGGL(uhat_kernel,      dim3(512),   dim3(256), 0, stream, ut, Wt2, u_hat);
    hipLaunchKernelGGL(routing_kernel,   dim3(512),   dim3(384), 0, stream, u_hat, out);
}